// Round 17
// baseline (1743.279 us; speedup 1.0000x reference)
//
#include <hip/hip_runtime.h>
#include <stdint.h>

#define BB 64
#define TT 1024
#define EE 128

typedef __bf16 bf16x8 __attribute__((ext_vector_type(8)));
typedef float f32x4 __attribute__((ext_vector_type(4)));

#define MFMA16 __builtin_amdgcn_mfma_f32_16x16x32_bf16

__device__ __forceinline__ float bf2f(unsigned short u) {
  union { unsigned int i; float f; } v; v.i = ((unsigned int)u) << 16; return v.f;
}
__device__ __forceinline__ unsigned short f2bf(float f) {
  union { float f; unsigned int i; } v; v.f = f;
  return (unsigned short)((v.i + 0x7fffu + ((v.i >> 16) & 1u)) >> 16);
}
// fast activations: v_rcp + native exp (avoid precise-div expansion)
__device__ __forceinline__ float sigf(float x) {
  return __builtin_amdgcn_rcpf(1.f + __expf(-x));
}
__device__ __forceinline__ float tanhf_(float x) {
  return fmaf(2.f, __builtin_amdgcn_rcpf(1.f + __expf(-2.f * x)), -1.f);
}

// ---------------- merged weight conversion (9 segments, one launch) ----------------

__global__ __launch_bounds__(256) void cvt_all(const float* s0, unsigned short* d0,
                                               const float* s1, unsigned short* d1,
                                               const float* s2, unsigned short* d2,
                                               const float* s3, unsigned short* d3,
                                               const float* s4, unsigned short* d4,
                                               const float* s5, unsigned short* d5,
                                               const float* s6, unsigned short* d6,
                                               const float* s7, unsigned short* d7,
                                               const float* s8, unsigned short* d8) {
  int i = blockIdx.x * 256 + threadIdx.x;   // in float4 units; total 180224
  const float* s; unsigned short* d; int off;
  if      (i <  16384) { s = s0; d = d0; off = 0; }
  else if (i <  32768) { s = s1; d = d1; off = 16384; }
  else if (i <  65536) { s = s2; d = d2; off = 32768; }
  else if (i <  98304) { s = s3; d = d3; off = 65536; }
  else if (i < 114688) { s = s4; d = d4; off = 98304; }
  else if (i < 131072) { s = s5; d = d5; off = 114688; }
  else if (i < 147456) { s = s6; d = d6; off = 131072; }
  else if (i < 163840) { s = s7; d = d7; off = 147456; }
  else                 { s = s8; d = d8; off = 163840; }
  int k = i - off;
  float4 v = *(const float4*)&s[(size_t)k * 4];
  ushort4 o; o.x = f2bf(v.x); o.y = f2bf(v.y); o.z = f2bf(v.z); o.w = f2bf(v.w);
  *(ushort4*)&d[(size_t)k * 4] = o;
}

__global__ __launch_bounds__(256) void bias_comb(const float* bi, const float* bh,
                                                 const float* bir, const float* bhr,
                                                 float* __restrict__ o) {
  int j = blockIdx.x * 256 + threadIdx.x;
  if (j < 1024) o[j] = (j < 512) ? (bi[j] + bh[j]) : (bir[j - 512] + bhr[j - 512]);
}

__global__ __launch_bounds__(256) void embed_k(const int* __restrict__ x,
                                               const float* __restrict__ emb,
                                               unsigned short* __restrict__ xe) {
  int i = blockIdx.x * 256 + threadIdx.x;   // B*T*E/4 = 2097152 threads
  int bt = i >> 5, e4 = (i & 31) << 2;      // E/4 = 32
  float4 v = *(const float4*)&emb[(size_t)x[bt] * EE + e4];
  ushort4 o; o.x = f2bf(v.x); o.y = f2bf(v.y); o.z = f2bf(v.z); o.w = f2bf(v.w);
  *(ushort4*)&xe[(size_t)bt * EE + e4] = o;
}

// ---------------- bf16 MFMA GEMM: 128x128 tile, BK=64, 4x4 acc/wave ----------------
// 256 threads = 4 waves; wave quadrant (wm,wn) = ((w&1)*64, (w>>1)*64).
// LDS: As/Ws 128x72 bf16 (pad 64->72); C staged in same LDS (stride 136) then
// copied out coalesced 128B/thread-row. [R12-proven correct]
// REMAP: row m=(b*T+t) written at ((t*B+b)*N + n) for LSTM "pre" (T,B,N).

template <bool RELU, bool REMAP>
__global__ __launch_bounds__(256) void gemm128(const unsigned short* __restrict__ A,
                                               const unsigned short* __restrict__ W,
                                               const float* __restrict__ bias,
                                               unsigned short* __restrict__ out,
                                               int M, int N, int K) {
  __shared__ unsigned short LB[2 * 128 * 72];          // As | Ws ; Cs aliases both
  const int tid = threadIdx.x, wave = tid >> 6, lane = tid & 63;
  const int fr = lane & 15, q = lane >> 4;
  const int m0 = blockIdx.x * 128, n0 = blockIdx.y * 128;
  const int wm = (wave & 1) * 64, wn = (wave >> 1) * 64;
  f32x4 acc[4][4] = {};
  const int sr = tid >> 1, sc = (tid & 1) * 32;        // staging: row, 32-elem chunk

  for (int k0 = 0; k0 < K; k0 += 64) {
    const unsigned short* ga = &A[(size_t)(m0 + sr) * K + k0 + sc];
    const unsigned short* gw = &W[(size_t)(n0 + sr) * K + k0 + sc];
    uint4 a0 = *(const uint4*)&ga[0],  a1 = *(const uint4*)&ga[8];
    uint4 a2 = *(const uint4*)&ga[16], a3 = *(const uint4*)&ga[24];
    uint4 w0 = *(const uint4*)&gw[0],  w1 = *(const uint4*)&gw[8];
    uint4 w2 = *(const uint4*)&gw[16], w3 = *(const uint4*)&gw[24];
    __syncthreads();                                   // prev iter's frag reads done
    *(uint4*)&LB[sr * 72 + sc +  0] = a0;
    *(uint4*)&LB[sr * 72 + sc +  8] = a1;
    *(uint4*)&LB[sr * 72 + sc + 16] = a2;
    *(uint4*)&LB[sr * 72 + sc + 24] = a3;
    *(uint4*)&LB[9216 + sr * 72 + sc +  0] = w0;
    *(uint4*)&LB[9216 + sr * 72 + sc +  8] = w1;
    *(uint4*)&LB[9216 + sr * 72 + sc + 16] = w2;
    *(uint4*)&LB[9216 + sr * 72 + sc + 24] = w3;
    __syncthreads();
#pragma unroll
    for (int kt = 0; kt < 2; kt++) {
      bf16x8 afr[4], bfr[4];
#pragma unroll
      for (int i = 0; i < 4; i++)
        afr[i] = *(const bf16x8*)&LB[(wm + i * 16 + fr) * 72 + kt * 32 + q * 8];
#pragma unroll
      for (int j = 0; j < 4; j++)
        bfr[j] = *(const bf16x8*)&LB[9216 + (wn + j * 16 + fr) * 72 + kt * 32 + q * 8];
#pragma unroll
      for (int i = 0; i < 4; i++)
#pragma unroll
        for (int j = 0; j < 4; j++)
          acc[i][j] = MFMA16(afr[i], bfr[j], acc[i][j], 0, 0, 0);
    }
  }
  __syncthreads();                                     // MFMA frag reads done -> reuse LDS
  // C layout (m89-verified): col = lane&15, row = (lane>>4)*4 + reg
  const int cc = fr, cr = q * 4;
#pragma unroll
  for (int j = 0; j < 4; j++) {
    float bs = bias[n0 + wn + j * 16 + cc];
#pragma unroll
    for (int i = 0; i < 4; i++)
#pragma unroll
      for (int rr = 0; rr < 4; rr++) {
        float v = acc[i][j][rr] + bs;
        if (RELU) v = fmaxf(v, 0.f);
        LB[(wm + i * 16 + cr + rr) * 136 + wn + j * 16 + cc] = f2bf(v);
      }
  }
  __syncthreads();
  // coalesced copy out: 2 threads/row, 128B each
  const int row = tid >> 1, hf = (tid & 1) * 64;
  const int gm = m0 + row;
  size_t off;
  if (REMAP) { int b = gm >> 10, t = gm & 1023; off = ((size_t)(t * 64 + b)) * N + n0 + hf; }
  else       { off = (size_t)gm * N + n0 + hf; }
#pragma unroll
  for (int j = 0; j < 8; j++) {
    uint4 v = *(const uint4*)&LB[row * 136 + hf + j * 8];
    *(uint4*)&out[off + j * 8] = v;
  }
}

// ---------------- LSTM recurrence v10: scan8 + 2-step-deep prefetch ----------------
// (R11/R15-measured: 528us/dispatch, VGPR 56, 0 conflicts -- unchanged)

#define SCAN_STEP10(PG0, PG1, PG2, PG3, TIDX) {                               \
    bf16x8 bv0 = *(const bf16x8*)&hS[p][q * 8];                               \
    bf16x8 bv1 = *(const bf16x8*)&hS[p][32 + q * 8];                          \
    bf16x8 bv2 = *(const bf16x8*)&hS[p][64 + q * 8];                          \
    bf16x8 bv3 = *(const bf16x8*)&hS[p][96 + q * 8];                          \
    f32x4 c0 = {0,0,0,0}, c1 = {0,0,0,0}, c2 = {0,0,0,0}, c3 = {0,0,0,0};     \
    c0 = MFMA16(bv0, af[0][0], c0, 0,0,0); c1 = MFMA16(bv0, af[1][0], c1, 0,0,0); \
    c2 = MFMA16(bv0, af[2][0], c2, 0,0,0); c3 = MFMA16(bv0, af[3][0], c3, 0,0,0); \
    c0 = MFMA16(bv1, af[0][1], c0, 0,0,0); c1 = MFMA16(bv1, af[1][1], c1, 0,0,0); \
    c2 = MFMA16(bv1, af[2][1], c2, 0,0,0); c3 = MFMA16(bv1, af[3][1], c3, 0,0,0); \
    c0 = MFMA16(bv2, af[0][2], c0, 0,0,0); c1 = MFMA16(bv2, af[1][2], c1, 0,0,0); \
    c2 = MFMA16(bv2, af[2][2], c2, 0,0,0); c3 = MFMA16(bv2, af[3][2], c3, 0,0,0); \
    c0 = MFMA16(bv3, af[0][3], c0, 0,0,0); c1 = MFMA16(bv3, af[1][3], c1, 0,0,0); \
    c2 = MFMA16(bv3, af[2][3], c2, 0,0,0); c3 = MFMA16(bv3, af[3][3], c3, 0,0,0); \
    float gi = c0[0] + bf2f(PG0);                                             \
    float gf = c1[0] + bf2f(PG1);                                             \
    float gg = c2[0] + bf2f(PG2);                                             \
    float go = c3[0] + bf2f(PG3);                                             \
    float cn = sigf(gf) * c + sigf(gi) * tanhf_(gg);                          \
    c = cn;                                                                   \
    float h = sigf(go) * tanhf_(cn);                                          \
    unsigned short hb_ = f2bf(h);                                             \
    if (q == 0) {                                                             \
      hS[p ^ 1][u] = hb_;                                                     \
      hob[(size_t)(TIDX) * 256] = hb_;  /* fire-and-forget */                 \
    }                                                                         \
  }

__global__ __launch_bounds__(512) void lstm_scan10(const unsigned short* __restrict__ pre,  // (T,B,1024) bf16
                                                   const unsigned short* __restrict__ whhb, // [2][512][128] bf16
                                                   unsigned short* __restrict__ hout) {     // (B,T,256) bf16
  const int b = blockIdx.x, dir = blockIdx.y;
  const int tid = threadIdx.x;
  const int w = tid >> 6, lane = tid & 63;
  const int fr = lane & 15, q = lane >> 4;
  const int u = 16 * w + fr;                    // this lane's unit
  const unsigned short* wb = whhb + (size_t)dir * 65536;

  // B-fragments: gate G tile = Whh rows [128G+16w, +16); lane holds row fr, k q*8
  bf16x8 af[4][4];
#pragma unroll
  for (int G = 0; G < 4; G++)
#pragma unroll
    for (int kt = 0; kt < 4; kt++)
      af[G][kt] = *(const bf16x8*)&wb[(size_t)(128 * G + 16 * w + fr) * 128 + kt * 32 + q * 8];
  asm volatile("" : "+v"(af[0][0]), "+v"(af[0][1]), "+v"(af[0][2]), "+v"(af[0][3]),
                    "+v"(af[1][0]), "+v"(af[1][1]), "+v"(af[1][2]), "+v"(af[1][3]),
                    "+v"(af[2][0]), "+v"(af[2][1]), "+v"(af[2][2]), "+v"(af[2][3]),
                    "+v"(af[3][0]), "+v"(af[3][1]), "+v"(af[3][2]), "+v"(af[3][3]));

  __shared__ alignas(16) unsigned short hS[2][128];
  if (tid < 128) { hS[0][tid] = 0; hS[1][tid] = 0; }

  const int t0 = dir ? 1023 : 0, st = dir ? -1 : 1;
  float c = 0.f;
  const unsigned short* pb = pre + (size_t)b * 1024 + dir * 512 + u;
  unsigned short* hob = hout + (size_t)b * 1024 * 256 + dir * 128 + u;

  // 2-step-deep prefetch: A = step s, B = step s+1
  unsigned short pA0, pA1, pA2, pA3, pB0, pB1, pB2, pB3;
  {
    size_t tb = (size_t)t0 * 65536;
    pA0 = pb[tb]; pA1 = pb[tb + 128]; pA2 = pb[tb + 256]; pA3 = pb[tb + 384];
    tb = (size_t)(t0 + st) * 65536;
    pB0 = pb[tb]; pB1 = pb[tb + 128]; pB2 = pb[tb + 256]; pB3 = pb[tb + 384];
  }
  __syncthreads();

  int p = 0;
  for (int s = 0; s < 1024; s += 2) {
    const int t = t0 + st * s;
    SCAN_STEP10(pA0, pA1, pA2, pA3, t)
    if (s + 2 < 1024) {
      size_t tb = (size_t)(t0 + st * (s + 2)) * 65536;
      pA0 = pb[tb]; pA1 = pb[tb + 128]; pA2 = pb[tb + 256]; pA3 = pb[tb + 384];
    }
    asm volatile("s_waitcnt lgkmcnt(0)\n\ts_barrier" ::: "memory");
    p ^= 1;
    SCAN_STEP10(pB0, pB1, pB2, pB3, t + st)
    if (s + 3 < 1024) {
      size_t tb = (size_t)(t0 + st * (s + 3)) * 65536;
      pB0 = pb[tb]; pB1 = pb[tb + 128]; pB2 = pb[tb + 256]; pB3 = pb[tb + 384];
    }
    asm volatile("s_waitcnt lgkmcnt(0)\n\ts_barrier" ::: "memory");
    p ^= 1;
  }
}

// ---------------- LayerNorm + attention score ----------------
// wave per (b,t) row of 256. input h bf16, output hln bf16.

__global__ __launch_bounds__(256) void ln_attn(const unsigned short* __restrict__ h,
                                               const float* __restrict__ g,
                                               const float* __restrict__ be,
                                               const float* __restrict__ aw,
                                               const float* __restrict__ ab,
                                               unsigned short* __restrict__ hln,
                                               float* __restrict__ sc) {
  int row = blockIdx.x * 4 + (threadIdx.x >> 6);
  int lane = threadIdx.x & 63;
  ushort4 u = *(const ushort4*)&h[(size_t)row * 256 + lane * 4];
  float vx = bf2f(u.x), vy = bf2f(u.y), vz = bf2f(u.z), vw = bf2f(u.w);
  float s = vx + vy + vz + vw;
#pragma unroll
  for (int o = 1; o < 64; o <<= 1) s += __shfl_xor(s, o);
  float mu = s * (1.f / 256.f);
  float dx = vx - mu, dy = vy - mu, dz = vz - mu, dw = vw - mu;
  float q = dx * dx + dy * dy + dz * dz + dw * dw;
#pragma unroll
  for (int o = 1; o < 64; o <<= 1) q += __shfl_xor(q, o);
  float inv = rsqrtf(q * (1.f / 256.f) + 1e-5f);
  float4 gg = *(const float4*)&g[lane * 4];
  float4 bb = *(const float4*)&be[lane * 4];
  float y0 = dx * inv * gg.x + bb.x;
  float y1 = dy * inv * gg.y + bb.y;
  float y2 = dz * inv * gg.z + bb.z;
  float y3 = dw * inv * gg.w + bb.w;
  ushort4 ov; ov.x = f2bf(y0); ov.y = f2bf(y1); ov.z = f2bf(y2); ov.w = f2bf(y3);
  *(ushort4*)&hln[(size_t)row * 256 + lane * 4] = ov;
  float4 av = *(const float4*)&aw[lane * 4];
  float p = y0 * av.x + y1 * av.y + y2 * av.z + y3 * av.w;
#pragma unroll
  for (int o = 1; o < 64; o <<= 1) p += __shfl_xor(p, o);
  if (lane == 0) sc[row] = p + ab[0];
}

// ---------------- masked softmax over T + weighted pooling ----------------
// grid (B, 4): block (b, cq) pools channels [64cq, 64cq+64) of batch b.
// softmax over scores recomputed per block (4KB redundant -- negligible).

__global__ __launch_bounds__(256) void attn_pool(const float* __restrict__ scores,
                                                 const int* __restrict__ x,
                                                 const unsigned short* __restrict__ h_ln,
                                                 float* __restrict__ pooled) {
  int b = blockIdx.x, cq = blockIdx.y, tid = threadIdx.x;
  __shared__ float wls[1024];
  __shared__ float red[4];
  float mx = -1e30f;
  for (int t = tid; t < 1024; t += 256) {
    bool valid = (t == 0) || (x[b * 1024 + t] != 0);
    float s = valid ? scores[b * 1024 + t] : -1e9f;
    wls[t] = s;
    mx = fmaxf(mx, s);
  }
#pragma unroll
  for (int o = 1; o < 64; o <<= 1) mx = fmaxf(mx, __shfl_xor(mx, o));
  if ((tid & 63) == 0) red[tid >> 6] = mx;
  __syncthreads();
  mx = fmaxf(fmaxf(red[0], red[1]), fmaxf(red[2], red[3]));
  __syncthreads();
  float sm = 0.f;
  for (int t = tid; t < 1024; t += 256) {
    float e = __expf(wls[t] - mx);
    wls[t] = e;
    sm += e;
  }
#pragma unroll
  for (int o = 1; o < 64; o <<= 1) sm += __shfl_xor(sm, o);
  if ((tid & 63) == 0) red[tid >> 6] = sm;
  __syncthreads();
  sm = red[0] + red[1] + red[2] + red[3];
  float inv = 1.f / sm;
  // 256 threads cover 64 channels x 4 t-phases; channel = 64cq + (tid&63)
  int ch = cq * 64 + (tid & 63), ph = tid >> 6;
  float a = 0.f;
  const unsigned short* hb = h_ln + (size_t)b * 1024 * 256 + ch;
  for (int t = ph; t < 1024; t += 4)
    a = fmaf(wls[t], bf2f(hb[(size_t)t * 256]), a);
  __syncthreads();
  // reduce the 4 phases via LDS (reuse wls)
  wls[ph * 64 + (tid & 63)] = a;
  __syncthreads();
  if (tid < 64) {
    float v = (wls[tid] + wls[64 + tid]) + (wls[128 + tid] + wls[192 + tid]);
    pooled[b * 256 + ch] = v * inv;
  }
}

__global__ __launch_bounds__(256) void h2add(const unsigned short* __restrict__ h_ln,
                                             const float* __restrict__ pooled,
                                             unsigned short* __restrict__ h2) {
  size_t i = ((size_t)blockIdx.x * 256 + threadIdx.x) * 4;
  int b = (int)(i >> 18);
  int cidx = (int)(i & 255);
  ushort4 v = *(const ushort4*)&h_ln[i];
  float4 p = *(const float4*)&pooled[b * 256 + cidx];
  ushort4 o;
  o.x = f2bf(bf2f(v.x) + p.x); o.y = f2bf(bf2f(v.y) + p.y);
  o.z = f2bf(bf2f(v.z) + p.z); o.w = f2bf(bf2f(v.w) + p.w);
  *(ushort4*)&h2[i] = o;
}

// ---------------- FC2 (N=20) ----------------

__global__ __launch_bounds__(256) void fc2_emis(const unsigned short* __restrict__ fin,
                                                const float* __restrict__ w,
                                                const float* __restrict__ bias,
                                                float* __restrict__ em) {
  int row = blockIdx.x * 4 + (threadIdx.x >> 6);
  int lane = threadIdx.x & 63;
  ushort4 u = *(const ushort4*)&fin[(size_t)row * 256 + lane * 4];
  float x0 = bf2f(u.x), x1 = bf2f(u.y), x2 = bf2f(u.z), x3 = bf2f(u.w);
  float acc[20];
#pragma unroll
  for (int jj = 0; jj < 20; jj++) {
    float4 wv = *(const float4*)&w[jj * 256 + lane * 4];
    acc[jj] = x0 * wv.x + x1 * wv.y + x2 * wv.z + x3 * wv.w;
  }
#pragma unroll
  for (int jj = 0; jj < 20; jj++) {
#pragma unroll
    for (int o = 1; o < 64; o <<= 1) acc[jj] += __shfl_xor(acc[jj], o);
  }
  if (lane == 0) {
#pragma unroll
    for (int jj = 0; jj < 20; jj++) em[(size_t)row * 20 + jj] = acc[jj] + bias[jj];
  }
}

// ---------------- CRF NLL ----------------

__global__ __launch_bounds__(64) void crf_k(const float* __restrict__ em,
                                            const int* __restrict__ tags,
                                            const int* __restrict__ x,
                                            const float* __restrict__ cs,
                                            const float* __restrict__ ce,
                                            const float* __restrict__ ctr,
                                            float* __restrict__ part) {
  int b = blockIdx.x, lane = threadIdx.x;
  const float* eb = em + (size_t)b * 1024 * 20;
  const int* tb = tags + b * 1024;
  const int* xb = x + b * 1024;

  int cnt = 0;
  for (int t = lane; t < 1024; t += 64) cnt += (t == 0 || xb[t] != 0) ? 1 : 0;
#pragma unroll
  for (int o = 1; o < 64; o <<= 1) cnt += __shfl_xor(cnt, o);
  int len = cnt;

  float ns = 0.f;
  for (int t = 1 + lane; t < len; t += 64)
    ns += ctr[tb[t - 1] * 20 + tb[t]] + eb[(size_t)t * 20 + tb[t]];
#pragma unroll
  for (int o = 1; o < 64; o <<= 1) ns += __shfl_xor(ns, o);
  float num = ns + cs[tb[0]] + eb[tb[0]] + ce[tb[len - 1]];

  __shared__ float al[32];
  if (lane < 32) al[lane] = (lane < 20) ? (cs[lane] + eb[lane]) : -1e30f;
  __syncthreads();

  int p = lane / 20, jj = lane % 20;
  int i0 = p * 7;
  float trc[7];
#pragma unroll
  for (int i = 0; i < 7; i++)
    trc[i] = (i0 + i < 20) ? ctr[(i0 + i) * 20 + jj] : -1e30f;

  for (int t = 1; t < len; t++) {
    float aa[7];
    float m = -3e30f;
#pragma unroll
    for (int i = 0; i < 7; i++) {
      float a = ((i0 + i < 28) ? al[i0 + i] : -1e30f) + trc[i];
      aa[i] = a;
      m = fmaxf(m, a);
    }
    float m0 = __shfl(m, jj), m1 = __shfl(m, jj + 20), m2 = __shfl(m, jj + 40);
    float mj = fmaxf(fmaxf(m0, m1), m2);
    float s = 0.f;
#pragma unroll
    for (int i = 0; i < 7; i++) s += __expf(aa[i] - mj);
    float s0 = __shfl(s, jj), s1 = __shfl(s, jj + 20), s2 = __shfl(s, jj + 40);
    float na = mj + __logf(s0 + s1 + s2) + eb[(size_t)t * 20 + jj];
    __syncthreads();
    if (lane < 20) al[lane] = na;
    __syncthreads();
  }

  float v = (lane < 20) ? (al[lane] + ce[lane]) : -3e30f;
  float mm = v;
#pragma unroll
  for (int o = 1; o < 64; o <<= 1) mm = fmaxf(mm, __shfl_xor(mm, o));
  float ss = (lane < 20) ? __expf(v - mm) : 0.f;
#pragma unroll
  for (int o = 1; o < 64; o <<= 1) ss += __shfl_xor(ss, o);
  float logZ = mm + __logf(ss);
  if (lane == 0) part[b] = logZ - num;
}

__global__ __launch_bounds__(64) void finalsum(const float* __restrict__ part,
                                               float* __restrict__ out) {
  float v = part[threadIdx.x];
#pragma unroll
  for (int o = 1; o < 64; o <<= 1) v += __shfl_xor(v, o);
  if (threadIdx.x == 0) out[0] = v;
}

// ---------------- host ----------------
// Workspace (liveness-aliased, peak ~162 MB)  [R11/R15 layout]:
//  region0 [0,128MB):  PRE bf16 (T,B,1024)             [gemm0->scan0, gemm1->scan1]
//    after scan1:      HLN bf16 32MB @0 | H2 bf16 32MB @64MB | FC1O bf16 32MB @96MB
//  region1 [128,160MB): XEMB -> HL0 -> HL1 -> EM
//  region2 [160MB+):   bf16 weights (incl WHHB0/1) + biases + SCORE + POOL + PART

extern "C" void kernel_launch(void* const* d_in, const int* in_sizes, int n_in,
                              void* d_out, int out_size, void* d_ws, size_t ws_size,
                              hipStream_t stream) {
  (void)in_sizes; (void)n_in; (void)out_size; (void)ws_size;
  const int*   x     = (const int*)  d_in[0];
  const int*   tags  = (const int*)  d_in[1];
  const float* emb   = (const float*)d_in[3];
  const float* wih0  = (const float*)d_in[4];
  const float* whh0  = (const float*)d_in[5];
  const float* bih0  = (const float*)d_in[6];
  const float* bhh0  = (const float*)d_in[7];
  const float* wih0r = (const float*)d_in[8];
  const float* whh0r = (const float*)d_in[9];
  const float* bih0r = (const float*)d_in[10];
  const float* bhh0r = (const float*)d_in[11];
  const float* wih1  = (const float*)d_in[12];
  const float* whh1  = (const float*)d_in[13];
  const float* bih1  = (const float*)d_in[14];
  const float* bhh1  = (const float*)d_in[15];
  const float* wih1r = (const float*)d_in[16];
  const float* whh1r = (const float*)d_in[17];
  const float* bih1r = (const float*)d_in[18];
  const float* bhh1r = (const float*)d_in[19];
  const float* lng   = (const float*)d_in[20];
  const float* lnb   = (const float*)d_in[21];
  const float* attw  = (const float*)d_in[22];
  const float* attb  = (const float*)d_in[23];
  const float* fc1w  = (const float*)d_in[24];
  const float* fc1b  = (const float*)d_in[25];
  const float* fc2w  = (const float*)d_in[26];
  const float* fc2b  = (const float*)d_in[27];
  const float* cst   = (const float*)d_in[28];
  const float* cen   = (const float*)d_in[29];
  const float* ctr   = (const float*)d_in[30];

  char* base = (char*)d_ws;
  const size_t MB = 1024 * 1024;

  // region0
  unsigned short* PRE  = (unsigned short*)(base);                 // 128MB bf16
  unsigned short* HLN  = (unsigned short*)(base);                 // 32MB bf16 (after PRE dead)
  unsigned short* H2   = (unsigned short*)(base + 64 * MB);       // 32MB bf16
  unsigned short* FC1O = (unsigned short*)(base + 96 * MB);       // 32MB bf16
  // region1
  unsigned short* XEMB = (unsigned short*)(base + 128 * MB);      // 16MB bf16
  unsigned short* HL0  = (unsigned short*)(base + 128 * MB);      // 32MB bf16
  unsigned short* HL1  = (unsigned short*)(base + 128 * MB);      // 32MB bf16
  float*          EM   = (float*)(base + 128 * MB);               // 5.25MB f32
  // region2: smalls
  char* sm = base + 160 * MB;
  unsigned short* WIH0  = (unsigned short*)sm;  sm += (size_t)2 * 512 * 128 * 2;  // 256KB
  unsigned short* WIH1  = (unsigned short*)sm;  sm += (size_t)2 * 512 * 256 * 2;  // 512KB
  unsigned short* FC1W  = (unsigned short*)sm;  sm += (size_t)256 * 256 * 2;      // 128KB
  unsigned short* WHHB0 = (unsigned short*)sm;  sm += (size_t)2 * 512 * 128 * 2;  // 256KB
  unsigned short* WHHB1 = (unsigned short*)sm;  sm += (size_t)2 * 512 * 128 * 2;  // 256KB
  float* BIAS0 = (float*)sm; sm += 1024 * 4;
  float* BIAS1 = (float*)sm; sm += 1024 * 4;
  float* SCORE = (float*)sm; sm += (size_t)BB * TT * 4;
  float* POOL  = (float*)sm; sm += 64 * 256 * 4;
  float* PART  = (float*)sm; sm += 256;

  // weight conversions (one launch) + combined biases
  cvt_all<<<704, 256, 0, stream>>>(wih0, WIH0,
                                   wih0r, WIH0 + 65536,
                                   wih1, WIH1,
                                   wih1r, WIH1 + 131072,
                                   fc1w, FC1W,
                                   whh0, WHHB0,
                                   whh0r, WHHB0 + 65536,
                                   whh1, WHHB1,
                                   whh1r, WHHB1 + 65536);
  bias_comb<<<4, 256, 0, stream>>>(bih0, bhh0, bih0r, bhh0r, BIAS0);
  bias_comb<<<4, 256, 0, stream>>>(bih1, bhh1, bih1r, bhh1r, BIAS1);

  // embedding gather
  embed_k<<<8192, 256, 0, stream>>>(x, emb, XEMB);

  // layer 0: input projection (both dirs fused, N=1024) + scan
  gemm128<false, true><<<dim3(512, 8), 256, 0, stream>>>(XEMB, WIH0, BIAS0, PRE, 65536, 1024, 128);
  lstm_scan10<<<dim3(64, 2), 512, 0, stream>>>(PRE, WHHB0, HL0);

  // layer 1
  gemm128<false, true><<<dim3(512, 8), 256, 0, stream>>>(HL0, WIH1, BIAS1, PRE, 65536, 1024, 256);
  lstm_scan10<<<dim3(64, 2), 512, 0, stream>>>(PRE, WHHB1, HL1);

  // layernorm + attention scores (PRE dead -> HLN overlays region0)
  ln_attn<<<16384, 256, 0, stream>>>(HL1, lng, lnb, attw, attb, HLN, SCORE);
  attn_pool<<<dim3(64, 4), 256, 0, stream>>>(SCORE, x, HLN, POOL);
  h2add<<<16384, 256, 0, stream>>>(HLN, POOL, H2);

  // FC1 (relu) + FC2
  gemm128<true, false><<<dim3(512, 2), 256, 0, stream>>>(H2, FC1W, fc1b, FC1O, 65536, 256, 256);
  fc2_emis<<<16384, 256, 0, stream>>>(FC1O, fc2w, fc2b, EM);

  // CRF
  crf_k<<<64, 64, 0, stream>>>(EM, tags, x, cst, cen, ctr, PART);
  finalsum<<<1, 64, 0, stream>>>(PART, (float*)d_out);
}

// Round 18
// 1693.473 us; speedup vs baseline: 1.0294x; 1.0294x over previous
//
#include <hip/hip_runtime.h>
#include <stdint.h>

#define BB 64
#define TT 1024
#define EE 128

typedef __bf16 bf16x8 __attribute__((ext_vector_type(8)));
typedef float f32x4 __attribute__((ext_vector_type(4)));

#define MFMA16 __builtin_amdgcn_mfma_f32_16x16x32_bf16

__device__ __forceinline__ float bf2f(unsigned short u) {
  union { unsigned int i; float f; } v; v.i = ((unsigned int)u) << 16; return v.f;
}
__device__ __forceinline__ unsigned short f2bf(float f) {
  union { float f; unsigned int i; } v; v.f = f;
  return (unsigned short)((v.i + 0x7fffu + ((v.i >> 16) & 1u)) >> 16);
}
// fast activations: v_rcp + native exp (avoid precise-div expansion)
__device__ __forceinline__ float sigf(float x) {
  return __builtin_amdgcn_rcpf(1.f + __expf(-x));
}
__device__ __forceinline__ float tanhf_(float x) {
  return fmaf(2.f, __builtin_amdgcn_rcpf(1.f + __expf(-2.f * x)), -1.f);
}

// ---------------- merged weight conversion (9 segments, one launch) ----------------

__global__ __launch_bounds__(256) void cvt_all(const float* s0, unsigned short* d0,
                                               const float* s1, unsigned short* d1,
                                               const float* s2, unsigned short* d2,
                                               const float* s3, unsigned short* d3,
                                               const float* s4, unsigned short* d4,
                                               const float* s5, unsigned short* d5,
                                               const float* s6, unsigned short* d6,
                                               const float* s7, unsigned short* d7,
                                               const float* s8, unsigned short* d8) {
  int i = blockIdx.x * 256 + threadIdx.x;   // in float4 units; total 180224
  const float* s; unsigned short* d; int off;
  if      (i <  16384) { s = s0; d = d0; off = 0; }
  else if (i <  32768) { s = s1; d = d1; off = 16384; }
  else if (i <  65536) { s = s2; d = d2; off = 32768; }
  else if (i <  98304) { s = s3; d = d3; off = 65536; }
  else if (i < 114688) { s = s4; d = d4; off = 98304; }
  else if (i < 131072) { s = s5; d = d5; off = 114688; }
  else if (i < 147456) { s = s6; d = d6; off = 131072; }
  else if (i < 163840) { s = s7; d = d7; off = 147456; }
  else                 { s = s8; d = d8; off = 163840; }
  int k = i - off;
  float4 v = *(const float4*)&s[(size_t)k * 4];
  ushort4 o; o.x = f2bf(v.x); o.y = f2bf(v.y); o.z = f2bf(v.z); o.w = f2bf(v.w);
  *(ushort4*)&d[(size_t)k * 4] = o;
}

__global__ __launch_bounds__(256) void bias_comb(const float* bi, const float* bh,
                                                 const float* bir, const float* bhr,
                                                 float* __restrict__ o) {
  int j = blockIdx.x * 256 + threadIdx.x;
  if (j < 1024) o[j] = (j < 512) ? (bi[j] + bh[j]) : (bir[j - 512] + bhr[j - 512]);
}

__global__ __launch_bounds__(256) void embed_k(const int* __restrict__ x,
                                               const float* __restrict__ emb,
                                               unsigned short* __restrict__ xe) {
  int i = blockIdx.x * 256 + threadIdx.x;   // B*T*E/4 = 2097152 threads
  int bt = i >> 5, e4 = (i & 31) << 2;      // E/4 = 32
  float4 v = *(const float4*)&emb[(size_t)x[bt] * EE + e4];
  ushort4 o; o.x = f2bf(v.x); o.y = f2bf(v.y); o.z = f2bf(v.z); o.w = f2bf(v.w);
  *(ushort4*)&xe[(size_t)bt * EE + e4] = o;
}

// ---------------- bf16 MFMA GEMM: C(M,N) = A(M,K) @ W(N,K)^T + bias ----------------
// 64x64 block tile, 256 threads (4 waves). Epilogue stages C in padded LDS then
// stores coalesced 32B/thread (128B contiguous per row).
// REMAP: output row m=(b*T+t) is written at ((t*B+b)*N + n)  (LSTM "pre" (T,B,N)).
// [R16-measured-best configuration]

template <bool RELU, bool REMAP>
__global__ __launch_bounds__(256) void gemm_bt(const unsigned short* __restrict__ A,
                                               const unsigned short* __restrict__ W,
                                               const float* __restrict__ bias,
                                               unsigned short* __restrict__ out,
                                               int M, int N, int K) {
  __shared__ unsigned short As[64][40];   // pad 32 -> 40 to break bank conflicts
  __shared__ unsigned short Ws[64][40];
  __shared__ unsigned short Cs[64][72];   // pad 64 -> 72: 2-way max on copy
  const int tid = threadIdx.x, wave = tid >> 6, lane = tid & 63;
  const int m0 = blockIdx.x * 64, n0 = blockIdx.y * 64;
  f32x4 acc[4] = {{0,0,0,0},{0,0,0,0},{0,0,0,0},{0,0,0,0}};
  const int r = tid >> 2, kc = (tid & 3) << 3;          // staging: row, k-offset(8 elems)
  const int fr = lane & 15, kk = (lane >> 4) << 3;      // fragment: row/col, k-offset

  for (int k0 = 0; k0 < K; k0 += 32) {
    uint4 av = *(const uint4*)&A[(size_t)(m0 + r) * K + k0 + kc];
    uint4 wv = *(const uint4*)&W[(size_t)(n0 + r) * K + k0 + kc];
    *(uint4*)&As[r][kc] = av;
    *(uint4*)&Ws[r][kc] = wv;
    __syncthreads();
    bf16x8 af = *(const bf16x8*)&As[wave * 16 + fr][kk];
#pragma unroll
    for (int nt = 0; nt < 4; nt++) {
      bf16x8 bv = *(const bf16x8*)&Ws[nt * 16 + fr][kk];
      acc[nt] = MFMA16(af, bv, acc[nt], 0, 0, 0);
    }
    __syncthreads();
  }
  // C layout (m89-verified): col = lane&15, row = (lane>>4)*4 + reg
  const int cr = (lane >> 4) << 2, cc = lane & 15;
#pragma unroll
  for (int nt = 0; nt < 4; nt++) {
    float bs = bias[n0 + nt * 16 + cc];
#pragma unroll
    for (int rr = 0; rr < 4; rr++) {
      float v = acc[nt][rr] + bs;
      if (RELU) v = fmaxf(v, 0.f);
      Cs[wave * 16 + cr + rr][nt * 16 + cc] = f2bf(v);
    }
  }
  __syncthreads();
  // coalesced store: thread copies one 32B chunk; 4 threads/row -> 128B/row
  const int row = tid >> 2, c0 = (tid & 3) * 16;
  uint4 v0 = *(const uint4*)&Cs[row][c0];
  uint4 v1 = *(const uint4*)&Cs[row][c0 + 8];
  const int gm = m0 + row;
  size_t off;
  if (REMAP) { int b = gm >> 10, t = gm & 1023; off = ((size_t)(t * 64 + b)) * N + n0 + c0; }
  else       { off = (size_t)gm * N + n0 + c0; }
  *(uint4*)&out[off] = v0;
  *(uint4*)&out[off + 8] = v1;
}

// ---------------- LSTM recurrence v10: scan8 + 2-step-deep prefetch ----------------
// (R11/R15/R16-measured: 528us/dispatch, VGPR 56, 0 conflicts)
// one block per (batch, direction); 512 threads = 8 waves; 128 blocks -> 128 CUs.
// gates^T = h x Whh^T (transposed MFMA); lane fr owns unit 16w+fr; activation
// lane-local; Whh frags pinned in 64 VGPRs; ONE lgkm-only barrier per step;
// pre prefetched TWO steps deep (HBM ~900cyc < 2-step slack).

#define SCAN_STEP10(PG0, PG1, PG2, PG3, TIDX) {                               \
    bf16x8 bv0 = *(const bf16x8*)&hS[p][q * 8];                               \
    bf16x8 bv1 = *(const bf16x8*)&hS[p][32 + q * 8];                          \
    bf16x8 bv2 = *(const bf16x8*)&hS[p][64 + q * 8];                          \
    bf16x8 bv3 = *(const bf16x8*)&hS[p][96 + q * 8];                          \
    f32x4 c0 = {0,0,0,0}, c1 = {0,0,0,0}, c2 = {0,0,0,0}, c3 = {0,0,0,0};     \
    c0 = MFMA16(bv0, af[0][0], c0, 0,0,0); c1 = MFMA16(bv0, af[1][0], c1, 0,0,0); \
    c2 = MFMA16(bv0, af[2][0], c2, 0,0,0); c3 = MFMA16(bv0, af[3][0], c3, 0,0,0); \
    c0 = MFMA16(bv1, af[0][1], c0, 0,0,0); c1 = MFMA16(bv1, af[1][1], c1, 0,0,0); \
    c2 = MFMA16(bv1, af[2][1], c2, 0,0,0); c3 = MFMA16(bv1, af[3][1], c3, 0,0,0); \
    c0 = MFMA16(bv2, af[0][2], c0, 0,0,0); c1 = MFMA16(bv2, af[1][2], c1, 0,0,0); \
    c2 = MFMA16(bv2, af[2][2], c2, 0,0,0); c3 = MFMA16(bv2, af[3][2], c3, 0,0,0); \
    c0 = MFMA16(bv3, af[0][3], c0, 0,0,0); c1 = MFMA16(bv3, af[1][3], c1, 0,0,0); \
    c2 = MFMA16(bv3, af[2][3], c2, 0,0,0); c3 = MFMA16(bv3, af[3][3], c3, 0,0,0); \
    float gi = c0[0] + bf2f(PG0);                                             \
    float gf = c1[0] + bf2f(PG1);                                             \
    float gg = c2[0] + bf2f(PG2);                                             \
    float go = c3[0] + bf2f(PG3);                                             \
    float cn = sigf(gf) * c + sigf(gi) * tanhf_(gg);                          \
    c = cn;                                                                   \
    float h = sigf(go) * tanhf_(cn);                                          \
    unsigned short hb_ = f2bf(h);                                             \
    if (q == 0) {                                                             \
      hS[p ^ 1][u] = hb_;                                                     \
      hob[(size_t)(TIDX) * 256] = hb_;  /* fire-and-forget */                 \
    }                                                                         \
  }

__global__ __launch_bounds__(512) void lstm_scan10(const unsigned short* __restrict__ pre,  // (T,B,1024) bf16
                                                   const unsigned short* __restrict__ whhb, // [2][512][128] bf16
                                                   unsigned short* __restrict__ hout) {     // (B,T,256) bf16
  const int b = blockIdx.x, dir = blockIdx.y;
  const int tid = threadIdx.x;
  const int w = tid >> 6, lane = tid & 63;
  const int fr = lane & 15, q = lane >> 4;
  const int u = 16 * w + fr;                    // this lane's unit
  const unsigned short* wb = whhb + (size_t)dir * 65536;

  // B-fragments: gate G tile = Whh rows [128G+16w, +16); lane holds row fr, k q*8
  bf16x8 af[4][4];
#pragma unroll
  for (int G = 0; G < 4; G++)
#pragma unroll
    for (int kt = 0; kt < 4; kt++)
      af[G][kt] = *(const bf16x8*)&wb[(size_t)(128 * G + 16 * w + fr) * 128 + kt * 32 + q * 8];
  asm volatile("" : "+v"(af[0][0]), "+v"(af[0][1]), "+v"(af[0][2]), "+v"(af[0][3]),
                    "+v"(af[1][0]), "+v"(af[1][1]), "+v"(af[1][2]), "+v"(af[1][3]),
                    "+v"(af[2][0]), "+v"(af[2][1]), "+v"(af[2][2]), "+v"(af[2][3]),
                    "+v"(af[3][0]), "+v"(af[3][1]), "+v"(af[3][2]), "+v"(af[3][3]));

  __shared__ alignas(16) unsigned short hS[2][128];
  if (tid < 128) { hS[0][tid] = 0; hS[1][tid] = 0; }

  const int t0 = dir ? 1023 : 0, st = dir ? -1 : 1;
  float c = 0.f;
  const unsigned short* pb = pre + (size_t)b * 1024 + dir * 512 + u;
  unsigned short* hob = hout + (size_t)b * 1024 * 256 + dir * 128 + u;

  // 2-step-deep prefetch: A = step s, B = step s+1
  unsigned short pA0, pA1, pA2, pA3, pB0, pB1, pB2, pB3;
  {
    size_t tb = (size_t)t0 * 65536;
    pA0 = pb[tb]; pA1 = pb[tb + 128]; pA2 = pb[tb + 256]; pA3 = pb[tb + 384];
    tb = (size_t)(t0 + st) * 65536;
    pB0 = pb[tb]; pB1 = pb[tb + 128]; pB2 = pb[tb + 256]; pB3 = pb[tb + 384];
  }
  __syncthreads();

  int p = 0;
  for (int s = 0; s < 1024; s += 2) {
    const int t = t0 + st * s;
    SCAN_STEP10(pA0, pA1, pA2, pA3, t)
    if (s + 2 < 1024) {
      size_t tb = (size_t)(t0 + st * (s + 2)) * 65536;
      pA0 = pb[tb]; pA1 = pb[tb + 128]; pA2 = pb[tb + 256]; pA3 = pb[tb + 384];
    }
    asm volatile("s_waitcnt lgkmcnt(0)\n\ts_barrier" ::: "memory");
    p ^= 1;
    SCAN_STEP10(pB0, pB1, pB2, pB3, t + st)
    if (s + 3 < 1024) {
      size_t tb = (size_t)(t0 + st * (s + 3)) * 65536;
      pB0 = pb[tb]; pB1 = pb[tb + 128]; pB2 = pb[tb + 256]; pB3 = pb[tb + 384];
    }
    asm volatile("s_waitcnt lgkmcnt(0)\n\ts_barrier" ::: "memory");
    p ^= 1;
  }
}

// ---------------- LayerNorm + attention score ----------------
// wave per (b,t) row of 256. input h bf16, output hln bf16 (halves traffic).

__global__ __launch_bounds__(256) void ln_attn(const unsigned short* __restrict__ h,
                                               const float* __restrict__ g,
                                               const float* __restrict__ be,
                                               const float* __restrict__ aw,
                                               const float* __restrict__ ab,
                                               unsigned short* __restrict__ hln,
                                               float* __restrict__ sc) {
  int row = blockIdx.x * 4 + (threadIdx.x >> 6);
  int lane = threadIdx.x & 63;
  ushort4 u = *(const ushort4*)&h[(size_t)row * 256 + lane * 4];
  float vx = bf2f(u.x), vy = bf2f(u.y), vz = bf2f(u.z), vw = bf2f(u.w);
  float s = vx + vy + vz + vw;
#pragma unroll
  for (int o = 1; o < 64; o <<= 1) s += __shfl_xor(s, o);
  float mu = s * (1.f / 256.f);
  float dx = vx - mu, dy = vy - mu, dz = vz - mu, dw = vw - mu;
  float q = dx * dx + dy * dy + dz * dz + dw * dw;
#pragma unroll
  for (int o = 1; o < 64; o <<= 1) q += __shfl_xor(q, o);
  float inv = rsqrtf(q * (1.f / 256.f) + 1e-5f);
  float4 gg = *(const float4*)&g[lane * 4];
  float4 bb = *(const float4*)&be[lane * 4];
  float y0 = dx * inv * gg.x + bb.x;
  float y1 = dy * inv * gg.y + bb.y;
  float y2 = dz * inv * gg.z + bb.z;
  float y3 = dw * inv * gg.w + bb.w;
  ushort4 ov; ov.x = f2bf(y0); ov.y = f2bf(y1); ov.z = f2bf(y2); ov.w = f2bf(y3);
  *(ushort4*)&hln[(size_t)row * 256 + lane * 4] = ov;
  float4 av = *(const float4*)&aw[lane * 4];
  float p = y0 * av.x + y1 * av.y + y2 * av.z + y3 * av.w;
#pragma unroll
  for (int o = 1; o < 64; o <<= 1) p += __shfl_xor(p, o);
  if (lane == 0) sc[row] = p + ab[0];
}

// ---------------- masked softmax over T + weighted pooling ----------------

__global__ __launch_bounds__(256) void attn_pool(const float* __restrict__ scores,
                                                 const int* __restrict__ x,
                                                 const unsigned short* __restrict__ h_ln,
                                                 float* __restrict__ pooled) {
  int b = blockIdx.x, tid = threadIdx.x;
  __shared__ float wls[1024];
  __shared__ float red[4];
  float mx = -1e30f;
  for (int t = tid; t < 1024; t += 256) {
    bool valid = (t == 0) || (x[b * 1024 + t] != 0);
    float s = valid ? scores[b * 1024 + t] : -1e9f;
    wls[t] = s;
    mx = fmaxf(mx, s);
  }
#pragma unroll
  for (int o = 1; o < 64; o <<= 1) mx = fmaxf(mx, __shfl_xor(mx, o));
  if ((tid & 63) == 0) red[tid >> 6] = mx;
  __syncthreads();
  mx = fmaxf(fmaxf(red[0], red[1]), fmaxf(red[2], red[3]));
  __syncthreads();
  float sm = 0.f;
  for (int t = tid; t < 1024; t += 256) {
    float e = __expf(wls[t] - mx);
    wls[t] = e;
    sm += e;
  }
#pragma unroll
  for (int o = 1; o < 64; o <<= 1) sm += __shfl_xor(sm, o);
  if ((tid & 63) == 0) red[tid >> 6] = sm;
  __syncthreads();
  sm = red[0] + red[1] + red[2] + red[3];
  float inv = 1.f / sm;
  float a0 = 0.f, a1 = 0.f, a2 = 0.f, a3 = 0.f;
  const unsigned short* hb = h_ln + (size_t)b * 1024 * 256 + tid;
  for (int t = 0; t < 1024; t += 4) {
    a0 = fmaf(wls[t + 0], bf2f(hb[(size_t)(t + 0) * 256]), a0);
    a1 = fmaf(wls[t + 1], bf2f(hb[(size_t)(t + 1) * 256]), a1);
    a2 = fmaf(wls[t + 2], bf2f(hb[(size_t)(t + 2) * 256]), a2);
    a3 = fmaf(wls[t + 3], bf2f(hb[(size_t)(t + 3) * 256]), a3);
  }
  pooled[b * 256 + tid] = ((a0 + a1) + (a2 + a3)) * inv;
}

__global__ __launch_bounds__(256) void h2add(const unsigned short* __restrict__ h_ln,
                                             const float* __restrict__ pooled,
                                             unsigned short* __restrict__ h2) {
  size_t i = ((size_t)blockIdx.x * 256 + threadIdx.x) * 4;
  int b = (int)(i >> 18);
  int cidx = (int)(i & 255);
  ushort4 v = *(const ushort4*)&h_ln[i];
  float4 p = *(const float4*)&pooled[b * 256 + cidx];
  ushort4 o;
  o.x = f2bf(bf2f(v.x) + p.x); o.y = f2bf(bf2f(v.y) + p.y);
  o.z = f2bf(bf2f(v.z) + p.z); o.w = f2bf(bf2f(v.w) + p.w);
  *(ushort4*)&h2[i] = o;
}

// ---------------- FC2 (N=20) ----------------

__global__ __launch_bounds__(256) void fc2_emis(const unsigned short* __restrict__ fin,
                                                const float* __restrict__ w,
                                                const float* __restrict__ bias,
                                                float* __restrict__ em) {
  int row = blockIdx.x * 4 + (threadIdx.x >> 6);
  int lane = threadIdx.x & 63;
  ushort4 u = *(const ushort4*)&fin[(size_t)row * 256 + lane * 4];
  float x0 = bf2f(u.x), x1 = bf2f(u.y), x2 = bf2f(u.z), x3 = bf2f(u.w);
  float acc[20];
#pragma unroll
  for (int jj = 0; jj < 20; jj++) {
    float4 wv = *(const float4*)&w[jj * 256 + lane * 4];
    acc[jj] = x0 * wv.x + x1 * wv.y + x2 * wv.z + x3 * wv.w;
  }
#pragma unroll
  for (int jj = 0; jj < 20; jj++) {
#pragma unroll
    for (int o = 1; o < 64; o <<= 1) acc[jj] += __shfl_xor(acc[jj], o);
  }
  if (lane == 0) {
#pragma unroll
    for (int jj = 0; jj < 20; jj++) em[(size_t)row * 20 + jj] = acc[jj] + bias[jj];
  }
}

// ---------------- CRF NLL ----------------

__global__ __launch_bounds__(64) void crf_k(const float* __restrict__ em,
                                            const int* __restrict__ tags,
                                            const int* __restrict__ x,
                                            const float* __restrict__ cs,
                                            const float* __restrict__ ce,
                                            const float* __restrict__ ctr,
                                            float* __restrict__ part) {
  int b = blockIdx.x, lane = threadIdx.x;
  const float* eb = em + (size_t)b * 1024 * 20;
  const int* tb = tags + b * 1024;
  const int* xb = x + b * 1024;

  int cnt = 0;
  for (int t = lane; t < 1024; t += 64) cnt += (t == 0 || xb[t] != 0) ? 1 : 0;
#pragma unroll
  for (int o = 1; o < 64; o <<= 1) cnt += __shfl_xor(cnt, o);
  int len = cnt;

  float ns = 0.f;
  for (int t = 1 + lane; t < len; t += 64)
    ns += ctr[tb[t - 1] * 20 + tb[t]] + eb[(size_t)t * 20 + tb[t]];
#pragma unroll
  for (int o = 1; o < 64; o <<= 1) ns += __shfl_xor(ns, o);
  float num = ns + cs[tb[0]] + eb[tb[0]] + ce[tb[len - 1]];

  __shared__ float al[32];
  if (lane < 32) al[lane] = (lane < 20) ? (cs[lane] + eb[lane]) : -1e30f;
  __syncthreads();

  int p = lane / 20, jj = lane % 20;
  int i0 = p * 7;
  float trc[7];
#pragma unroll
  for (int i = 0; i < 7; i++)
    trc[i] = (i0 + i < 20) ? ctr[(i0 + i) * 20 + jj] : -1e30f;

  for (int t = 1; t < len; t++) {
    float aa[7];
    float m = -3e30f;
#pragma unroll
    for (int i = 0; i < 7; i++) {
      float a = ((i0 + i < 28) ? al[i0 + i] : -1e30f) + trc[i];
      aa[i] = a;
      m = fmaxf(m, a);
    }
    float m0 = __shfl(m, jj), m1 = __shfl(m, jj + 20), m2 = __shfl(m, jj + 40);
    float mj = fmaxf(fmaxf(m0, m1), m2);
    float s = 0.f;
#pragma unroll
    for (int i = 0; i < 7; i++) s += __expf(aa[i] - mj);
    float s0 = __shfl(s, jj), s1 = __shfl(s, jj + 20), s2 = __shfl(s, jj + 40);
    float na = mj + __logf(s0 + s1 + s2) + eb[(size_t)t * 20 + jj];
    __syncthreads();
    if (lane < 20) al[lane] = na;
    __syncthreads();
  }

  float v = (lane < 20) ? (al[lane] + ce[lane]) : -3e30f;
  float mm = v;
#pragma unroll
  for (int o = 1; o < 64; o <<= 1) mm = fmaxf(mm, __shfl_xor(mm, o));
  float ss = (lane < 20) ? __expf(v - mm) : 0.f;
#pragma unroll
  for (int o = 1; o < 64; o <<= 1) ss += __shfl_xor(ss, o);
  float logZ = mm + __logf(ss);
  if (lane == 0) part[b] = logZ - num;
}

__global__ __launch_bounds__(64) void finalsum(const float* __restrict__ part,
                                               float* __restrict__ out) {
  float v = part[threadIdx.x];
#pragma unroll
  for (int o = 1; o < 64; o <<= 1) v += __shfl_xor(v, o);
  if (threadIdx.x == 0) out[0] = v;
}

// ---------------- host ----------------
// Workspace (liveness-aliased, peak ~162 MB)  [R16-measured-best layout]:
//  region0 [0,128MB):  PRE bf16 (T,B,1024)             [gemm0->scan0, gemm1->scan1]
//    after scan1:      HLN bf16 32MB @0 | H2 bf16 32MB @64MB | FC1O bf16 32MB @96MB
//  region1 [128,160MB): XEMB -> HL0 -> HL1 -> EM
//  region2 [160MB+):   bf16 weights (incl WHHB0/1) + biases + SCORE + POOL + PART

extern "C" void kernel_launch(void* const* d_in, const int* in_sizes, int n_in,
                              void* d_out, int out_size, void* d_ws, size_t ws_size,
                              hipStream_t stream) {
  (void)in_sizes; (void)n_in; (void)out_size; (void)ws_size;
  const int*   x     = (const int*)  d_in[0];
  const int*   tags  = (const int*)  d_in[1];
  const float* emb   = (const float*)d_in[3];
  const float* wih0  = (const float*)d_in[4];
  const float* whh0  = (const float*)d_in[5];
  const float* bih0  = (const float*)d_in[6];
  const float* bhh0  = (const float*)d_in[7];
  const float* wih0r = (const float*)d_in[8];
  const float* whh0r = (const float*)d_in[9];
  const float* bih0r = (const float*)d_in[10];
  const float* bhh0r = (const float*)d_in[11];
  const float* wih1  = (const float*)d_in[12];
  const float* whh1  = (const float*)d_in[13];
  const float* bih1  = (const float*)d_in[14];
  const float* bhh1  = (const float*)d_in[15];
  const float* wih1r = (const float*)d_in[16];
  const float* whh1r = (const float*)d_in[17];
  const float* bih1r = (const float*)d_in[18];
  const float* bhh1r = (const float*)d_in[19];
  const float* lng   = (const float*)d_in[20];
  const float* lnb   = (const float*)d_in[21];
  const float* attw  = (const float*)d_in[22];
  const float* attb  = (const float*)d_in[23];
  const float* fc1w  = (const float*)d_in[24];
  const float* fc1b  = (const float*)d_in[25];
  const float* fc2w  = (const float*)d_in[26];
  const float* fc2b  = (const float*)d_in[27];
  const float* cst   = (const float*)d_in[28];
  const float* cen   = (const float*)d_in[29];
  const float* ctr   = (const float*)d_in[30];

  char* base = (char*)d_ws;
  const size_t MB = 1024 * 1024;

  // region0
  unsigned short* PRE  = (unsigned short*)(base);                 // 128MB bf16
  unsigned short* HLN  = (unsigned short*)(base);                 // 32MB bf16 (after PRE dead)
  unsigned short* H2   = (unsigned short*)(base + 64 * MB);       // 32MB bf16
  unsigned short* FC1O = (unsigned short*)(base + 96 * MB);       // 32MB bf16
  // region1
  unsigned short* XEMB = (unsigned short*)(base + 128 * MB);      // 16MB bf16
  unsigned short* HL0  = (unsigned short*)(base + 128 * MB);      // 32MB bf16
  unsigned short* HL1  = (unsigned short*)(base + 128 * MB);      // 32MB bf16
  float*          EM   = (float*)(base + 128 * MB);               // 5.25MB f32
  // region2: smalls
  char* sm = base + 160 * MB;
  unsigned short* WIH0  = (unsigned short*)sm;  sm += (size_t)2 * 512 * 128 * 2;  // 256KB
  unsigned short* WIH1  = (unsigned short*)sm;  sm += (size_t)2 * 512 * 256 * 2;  // 512KB
  unsigned short* FC1W  = (unsigned short*)sm;  sm += (size_t)256 * 256 * 2;      // 128KB
  unsigned short* WHHB0 = (unsigned short*)sm;  sm += (size_t)2 * 512 * 128 * 2;  // 256KB
  unsigned short* WHHB1 = (unsigned short*)sm;  sm += (size_t)2 * 512 * 128 * 2;  // 256KB
  float* BIAS0 = (float*)sm; sm += 1024 * 4;
  float* BIAS1 = (float*)sm; sm += 1024 * 4;
  float* SCORE = (float*)sm; sm += (size_t)BB * TT * 4;
  float* POOL  = (float*)sm; sm += 64 * 256 * 4;
  float* PART  = (float*)sm; sm += 256;

  // weight conversions (one launch) + combined biases
  cvt_all<<<704, 256, 0, stream>>>(wih0, WIH0,
                                   wih0r, WIH0 + 65536,
                                   wih1, WIH1,
                                   wih1r, WIH1 + 131072,
                                   fc1w, FC1W,
                                   whh0, WHHB0,
                                   whh0r, WHHB0 + 65536,
                                   whh1, WHHB1,
                                   whh1r, WHHB1 + 65536);
  bias_comb<<<4, 256, 0, stream>>>(bih0, bhh0, bih0r, bhh0r, BIAS0);
  bias_comb<<<4, 256, 0, stream>>>(bih1, bhh1, bih1r, bhh1r, BIAS1);

  // embedding gather
  embed_k<<<8192, 256, 0, stream>>>(x, emb, XEMB);

  // layer 0: input projection (both dirs fused, N=1024) + scan
  gemm_bt<false, true><<<dim3(1024, 16), 256, 0, stream>>>(XEMB, WIH0, BIAS0, PRE, 65536, 1024, 128);
  lstm_scan10<<<dim3(64, 2), 512, 0, stream>>>(PRE, WHHB0, HL0);

  // layer 1
  gemm_bt<false, true><<<dim3(1024, 16), 256, 0, stream>>>(HL0, WIH1, BIAS1, PRE, 65536, 1024, 256);
  lstm_scan10<<<dim3(64, 2), 512, 0, stream>>>(PRE, WHHB1, HL1);

  // layernorm + attention scores (PRE dead -> HLN overlays region0)
  ln_attn<<<16384, 256, 0, stream>>>(HL1, lng, lnb, attw, attb, HLN, SCORE);
  attn_pool<<<64, 256, 0, stream>>>(SCORE, x, HLN, POOL);
  h2add<<<16384, 256, 0, stream>>>(HLN, POOL, H2);

  // FC1 (relu) + FC2
  gemm_bt<true, false><<<dim3(1024, 4), 256, 0, stream>>>(H2, FC1W, fc1b, FC1O, 65536, 256, 256);
  fc2_emis<<<16384, 256, 0, stream>>>(FC1O, fc2w, fc2b, EM);

  // CRF
  crf_k<<<64, 64, 0, stream>>>(EM, tags, x, cst, cen, ctr, PART);
  finalsum<<<1, 64, 0, stream>>>(PART, (float*)d_out);
}